// Round 1
// baseline (67.125 us; speedup 1.0000x reference)
//
#include <hip/hip_runtime.h>

#define N_NODES 8192
#define T_TYPES 8
#define HIN 256     // H*IN
#define OUTF 64
#define G3 192      // 3*OUT
#define BM 32       // nodes per block

__global__ __launch_bounds__(64) void zero_cursors(int* c) {
    if (threadIdx.x < T_TYPES) c[threadIdx.x] = 0;
}

// Wave-aggregated counting scatter: perm[t*N + pos] = node index, cursors[t] = count.
__global__ __launch_bounds__(256) void scatter_by_type(const int* __restrict__ nt,
                                                       int* __restrict__ cursors,
                                                       int* __restrict__ perm) {
    int i = blockIdx.x * 256 + threadIdx.x;
    int lane = threadIdx.x & 63;
    int t = nt[i];
    unsigned long long below = (1ull << lane) - 1ull;
    #pragma unroll
    for (int tt = 0; tt < T_TYPES; ++tt) {
        bool mine = (t == tt);
        unsigned long long mask = __ballot(mine);
        if (mask == 0ull) continue;
        int leader = __ffsll(mask) - 1;
        int cnt = __popcll(mask);
        int base = 0;
        if (lane == leader) base = atomicAdd(&cursors[tt], cnt);
        base = __shfl(base, leader, 64);
        if (mine) perm[tt * N_NODES + base + __popcll(mask & below)] = i;
    }
}

__global__ __launch_bounds__(256) void fused_rgnn(
    const float* __restrict__ agg, const float* __restrict__ h,
    const int* __restrict__ cursors, const int* __restrict__ perm,
    const float* __restrict__ W_att, const float* __restrict__ b_att,
    const float* __restrict__ W_in, const float* __restrict__ W_hid,
    const float* __restrict__ b_in, const float* __restrict__ b_hid,
    float* __restrict__ out)
{
    __shared__ float Xs[BM][HIN];   // 32 KB
    __shared__ float Ys[BM][OUTF];  // 8 KB
    __shared__ float Hs[BM][OUTF];  // 8 KB
    __shared__ int idxs[BM];

    const int tid = threadIdx.x;
    const int t = blockIdx.x >> 8;       // type
    const int chunk = blockIdx.x & 255;  // chunk within type
    const int cnt = cursors[t];
    const int m0 = chunk * BM;
    if (m0 >= cnt) return;
    const int mcnt = min(BM, cnt - m0);

    if (tid < BM) idxs[tid] = (tid < mcnt) ? perm[t * N_NODES + m0 + tid] : 0;
    __syncthreads();

    // Stage X = relu(agg_msg[idx]) and H = h[idx] (float4, coalesced per node row).
    {
        int c4 = (tid & 63) << 2;   // 0..252
        int nb = tid >> 6;          // 0..3
        #pragma unroll
        for (int k = 0; k < 8; ++k) {
            int node = (k << 2) + nb;
            float4 v = make_float4(0.f, 0.f, 0.f, 0.f);
            if (node < mcnt) v = *(const float4*)&agg[(size_t)idxs[node] * HIN + c4];
            v.x = fmaxf(v.x, 0.f); v.y = fmaxf(v.y, 0.f);
            v.z = fmaxf(v.z, 0.f); v.w = fmaxf(v.w, 0.f);
            *(float4*)&Xs[node][c4] = v;
        }
        int d4 = (tid & 15) << 2;   // 0..60
        int nb2 = tid >> 4;         // 0..15
        #pragma unroll
        for (int k = 0; k < 2; ++k) {
            int node = (k << 4) + nb2;
            float4 v = make_float4(0.f, 0.f, 0.f, 0.f);
            if (node < mcnt) v = *(const float4*)&h[(size_t)idxs[node] * OUTF + d4];
            *(float4*)&Hs[node][d4] = v;
        }
    }
    __syncthreads();

    const int col = tid & 63;   // output column
    const int jb = tid >> 6;    // node quadrant (8 nodes each)

    // Phase 2: Y = relu(X @ W_att[t] + b_att[t])   [32 x 64]
    float acc[8];
    #pragma unroll
    for (int j = 0; j < 8; ++j) acc[j] = 0.f;
    const float* Wa = W_att + (size_t)t * HIN * OUTF;
    for (int d0 = 0; d0 < HIN; d0 += 4) {
        float w0 = Wa[(d0 + 0) * OUTF + col];
        float w1 = Wa[(d0 + 1) * OUTF + col];
        float w2 = Wa[(d0 + 2) * OUTF + col];
        float w3 = Wa[(d0 + 3) * OUTF + col];
        #pragma unroll
        for (int j = 0; j < 8; ++j) {
            float4 x = *(const float4*)&Xs[(jb << 3) + j][d0];
            acc[j] = fmaf(x.w, w3, fmaf(x.z, w2, fmaf(x.y, w1, fmaf(x.x, w0, acc[j]))));
        }
    }
    {
        float ba = b_att[t * OUTF + col];
        #pragma unroll
        for (int j = 0; j < 8; ++j)
            Ys[(jb << 3) + j][col] = fmaxf(acc[j] + ba, 0.f);
    }
    __syncthreads();

    // Phase 3+4: gi = Y @ W_in[t], gh = H @ W_hid[t], all 6 gate slices in registers.
    const float* Wi = W_in  + (size_t)t * OUTF * G3;
    const float* Wh = W_hid + (size_t)t * OUTF * G3;
    float ir[8], iz[8], inn[8], hr[8], hz[8], hn[8];
    #pragma unroll
    for (int j = 0; j < 8; ++j) { ir[j]=0.f; iz[j]=0.f; inn[j]=0.f; hr[j]=0.f; hz[j]=0.f; hn[j]=0.f; }
    for (int kk = 0; kk < OUTF; ++kk) {
        float wir = Wi[kk * G3 + col];
        float wiz = Wi[kk * G3 + 64 + col];
        float win = Wi[kk * G3 + 128 + col];
        float whr = Wh[kk * G3 + col];
        float whz = Wh[kk * G3 + 64 + col];
        float whn = Wh[kk * G3 + 128 + col];
        #pragma unroll
        for (int j = 0; j < 8; ++j) {
            float y  = Ys[(jb << 3) + j][kk];
            float hh = Hs[(jb << 3) + j][kk];
            ir[j]  = fmaf(y,  wir, ir[j]);
            iz[j]  = fmaf(y,  wiz, iz[j]);
            inn[j] = fmaf(y,  win, inn[j]);
            hr[j]  = fmaf(hh, whr, hr[j]);
            hz[j]  = fmaf(hh, whz, hz[j]);
            hn[j]  = fmaf(hh, whn, hn[j]);
        }
    }

    // Epilogue: GRU gates + scatter store.
    {
        float bir = b_in[t * G3 + col];
        float biz = b_in[t * G3 + 64 + col];
        float bin_ = b_in[t * G3 + 128 + col];
        float bhr = b_hid[t * G3 + col];
        float bhz = b_hid[t * G3 + 64 + col];
        float bhn = b_hid[t * G3 + 128 + col];
        #pragma unroll
        for (int j = 0; j < 8; ++j) {
            int node = (jb << 3) + j;
            if (node < mcnt) {
                float rv = ir[j] + bir + hr[j] + bhr;
                float r = 1.f / (1.f + __expf(-rv));
                float zv = iz[j] + biz + hz[j] + bhz;
                float z = 1.f / (1.f + __expf(-zv));
                float nn = tanhf(inn[j] + bin_ + r * (hn[j] + bhn));
                float hv = Hs[node][col];
                out[(size_t)idxs[node] * OUTF + col] = (1.f - z) * nn + z * hv;
            }
        }
    }
}

extern "C" void kernel_launch(void* const* d_in, const int* in_sizes, int n_in,
                              void* d_out, int out_size, void* d_ws, size_t ws_size,
                              hipStream_t stream) {
    const float* agg   = (const float*)d_in[0];
    const float* h     = (const float*)d_in[1];
    const int*   ntype = (const int*)d_in[2];
    const float* W_att = (const float*)d_in[3];
    const float* b_att = (const float*)d_in[4];
    const float* W_in  = (const float*)d_in[5];
    const float* W_hid = (const float*)d_in[6];
    const float* b_in  = (const float*)d_in[7];
    const float* b_hid = (const float*)d_in[8];
    float* out = (float*)d_out;

    int* cursors = (int*)d_ws;
    int* perm = cursors + 16;   // 64-byte offset; perm needs T*N*4 = 256 KB

    zero_cursors<<<1, 64, 0, stream>>>(cursors);
    scatter_by_type<<<N_NODES / 256, 256, 0, stream>>>(ntype, cursors, perm);
    fused_rgnn<<<T_TYPES * 256, 256, 0, stream>>>(agg, h, cursors, perm,
        W_att, b_att, W_in, W_hid, b_in, b_hid, out);
}

// Round 2
// 55.632 us; speedup vs baseline: 1.2066x; 1.2066x over previous
//
#include <hip/hip_runtime.h>

#define N_NODES 8192
#define T_TYPES 8
#define HIN 256     // H*IN
#define OUTF 64
#define G3 192      // 3*OUT
#define BM 8        // nodes per block (small tile -> high occupancy)
#define CHUNKS_PER_TYPE (N_NODES / BM)   // 1024 (worst case: all nodes one type)

__global__ __launch_bounds__(64) void zero_cursors(int* c) {
    if (threadIdx.x < T_TYPES) c[threadIdx.x] = 0;
}

// Wave-aggregated counting scatter: perm[t*N + pos] = node index, cursors[t] = count.
__global__ __launch_bounds__(256) void scatter_by_type(const int* __restrict__ nt,
                                                       int* __restrict__ cursors,
                                                       int* __restrict__ perm) {
    int i = blockIdx.x * 256 + threadIdx.x;
    int lane = threadIdx.x & 63;
    int t = nt[i];
    unsigned long long below = (1ull << lane) - 1ull;
    #pragma unroll
    for (int tt = 0; tt < T_TYPES; ++tt) {
        bool mine = (t == tt);
        unsigned long long mask = __ballot(mine);
        if (mask == 0ull) continue;
        int leader = __ffsll(mask) - 1;
        int cnt = __popcll(mask);
        int base = 0;
        if (lane == leader) base = atomicAdd(&cursors[tt], cnt);
        base = __shfl(base, leader, 64);
        if (mine) perm[tt * N_NODES + base + __popcll(mask & below)] = i;
    }
}

__global__ __launch_bounds__(256) void fused_rgnn(
    const float* __restrict__ agg, const float* __restrict__ h,
    const int* __restrict__ cursors, const int* __restrict__ perm,
    const float* __restrict__ W_att, const float* __restrict__ b_att,
    const float* __restrict__ W_in, const float* __restrict__ W_hid,
    const float* __restrict__ b_in, const float* __restrict__ b_hid,
    float* __restrict__ out)
{
    __shared__ float Xs[BM][HIN];   // 8 KB
    __shared__ float Ys[BM][OUTF];  // 2 KB
    __shared__ float Hs[BM][OUTF];  // 2 KB
    __shared__ int idxs[BM];

    const int tid = threadIdx.x;
    const int t = blockIdx.x / CHUNKS_PER_TYPE;       // type
    const int chunk = blockIdx.x % CHUNKS_PER_TYPE;   // chunk within type
    const int cnt = cursors[t];
    const int m0 = chunk * BM;
    if (m0 >= cnt) return;                            // uniform early exit
    const int mcnt = min(BM, cnt - m0);

    if (tid < BM) idxs[tid] = (tid < mcnt) ? perm[t * N_NODES + m0 + tid] : 0;
    __syncthreads();

    // Stage X = relu(agg_msg[idx]) (each thread: 2 float4) and H = h[idx].
    {
        int c4 = (tid & 63) << 2;   // 0..252
        int nb = tid >> 6;          // 0..3
        #pragma unroll
        for (int k = 0; k < 2; ++k) {
            int node = (k << 2) + nb;               // 0..7
            float4 v = make_float4(0.f, 0.f, 0.f, 0.f);
            if (node < mcnt) v = *(const float4*)&agg[(size_t)idxs[node] * HIN + c4];
            v.x = fmaxf(v.x, 0.f); v.y = fmaxf(v.y, 0.f);
            v.z = fmaxf(v.z, 0.f); v.w = fmaxf(v.w, 0.f);
            *(float4*)&Xs[node][c4] = v;
        }
        if (tid < 128) {
            int d4 = (tid & 15) << 2;   // 0..60
            int node = tid >> 4;        // 0..7
            float4 v = make_float4(0.f, 0.f, 0.f, 0.f);
            if (node < mcnt) v = *(const float4*)&h[(size_t)idxs[node] * OUTF + d4];
            *(float4*)&Hs[node][d4] = v;
        }
    }
    __syncthreads();

    const int col = tid & 63;   // output column
    const int jb = tid >> 6;    // node pair group (2 nodes each)

    // Phase 2: Y = relu(X @ W_att[t] + b_att[t])   [8 x 64]
    float acc[2] = {0.f, 0.f};
    const float* Wa = W_att + (size_t)t * HIN * OUTF;
    #pragma unroll 4
    for (int d0 = 0; d0 < HIN; d0 += 4) {
        float w0 = Wa[(d0 + 0) * OUTF + col];
        float w1 = Wa[(d0 + 1) * OUTF + col];
        float w2 = Wa[(d0 + 2) * OUTF + col];
        float w3 = Wa[(d0 + 3) * OUTF + col];
        #pragma unroll
        for (int j = 0; j < 2; ++j) {
            float4 x = *(const float4*)&Xs[(jb << 1) + j][d0];
            acc[j] = fmaf(x.w, w3, fmaf(x.z, w2, fmaf(x.y, w1, fmaf(x.x, w0, acc[j]))));
        }
    }
    {
        float ba = b_att[t * OUTF + col];
        #pragma unroll
        for (int j = 0; j < 2; ++j)
            Ys[(jb << 1) + j][col] = fmaxf(acc[j] + ba, 0.f);
    }
    __syncthreads();

    // Phase 3+4: gi = Y @ W_in[t], gh = H @ W_hid[t], all 6 gate slices in registers.
    const float* Wi = W_in  + (size_t)t * OUTF * G3;
    const float* Wh = W_hid + (size_t)t * OUTF * G3;
    float ir[2], iz[2], inn[2], hr[2], hz[2], hn[2];
    #pragma unroll
    for (int j = 0; j < 2; ++j) { ir[j]=0.f; iz[j]=0.f; inn[j]=0.f; hr[j]=0.f; hz[j]=0.f; hn[j]=0.f; }
    #pragma unroll 4
    for (int kk = 0; kk < OUTF; ++kk) {
        float wir = Wi[kk * G3 + col];
        float wiz = Wi[kk * G3 + 64 + col];
        float win = Wi[kk * G3 + 128 + col];
        float whr = Wh[kk * G3 + col];
        float whz = Wh[kk * G3 + 64 + col];
        float whn = Wh[kk * G3 + 128 + col];
        #pragma unroll
        for (int j = 0; j < 2; ++j) {
            float y  = Ys[(jb << 1) + j][kk];
            float hh = Hs[(jb << 1) + j][kk];
            ir[j]  = fmaf(y,  wir, ir[j]);
            iz[j]  = fmaf(y,  wiz, iz[j]);
            inn[j] = fmaf(y,  win, inn[j]);
            hr[j]  = fmaf(hh, whr, hr[j]);
            hz[j]  = fmaf(hh, whz, hz[j]);
            hn[j]  = fmaf(hh, whn, hn[j]);
        }
    }

    // Epilogue: GRU gates + scatter store.
    {
        float bir = b_in[t * G3 + col];
        float biz = b_in[t * G3 + 64 + col];
        float bin_ = b_in[t * G3 + 128 + col];
        float bhr = b_hid[t * G3 + col];
        float bhz = b_hid[t * G3 + 64 + col];
        float bhn = b_hid[t * G3 + 128 + col];
        #pragma unroll
        for (int j = 0; j < 2; ++j) {
            int node = (jb << 1) + j;
            if (node < mcnt) {
                float rv = ir[j] + bir + hr[j] + bhr;
                float r = 1.f / (1.f + __expf(-rv));
                float zv = iz[j] + biz + hz[j] + bhz;
                float z = 1.f / (1.f + __expf(-zv));
                float nn = tanhf(inn[j] + bin_ + r * (hn[j] + bhn));
                float hv = Hs[node][col];
                out[(size_t)idxs[node] * OUTF + col] = (1.f - z) * nn + z * hv;
            }
        }
    }
}

extern "C" void kernel_launch(void* const* d_in, const int* in_sizes, int n_in,
                              void* d_out, int out_size, void* d_ws, size_t ws_size,
                              hipStream_t stream) {
    const float* agg   = (const float*)d_in[0];
    const float* h     = (const float*)d_in[1];
    const int*   ntype = (const int*)d_in[2];
    const float* W_att = (const float*)d_in[3];
    const float* b_att = (const float*)d_in[4];
    const float* W_in  = (const float*)d_in[5];
    const float* W_hid = (const float*)d_in[6];
    const float* b_in  = (const float*)d_in[7];
    const float* b_hid = (const float*)d_in[8];
    float* out = (float*)d_out;

    int* cursors = (int*)d_ws;
    int* perm = cursors + 16;   // perm needs T*N*4 = 256 KB of d_ws

    zero_cursors<<<1, 64, 0, stream>>>(cursors);
    scatter_by_type<<<N_NODES / 256, 256, 0, stream>>>(ntype, cursors, perm);
    fused_rgnn<<<T_TYPES * CHUNKS_PER_TYPE, 256, 0, stream>>>(agg, h, cursors, perm,
        W_att, b_att, W_in, W_hid, b_in, b_hid, out);
}

// Round 3
// 36.989 us; speedup vs baseline: 1.8147x; 1.5040x over previous
//
#include <hip/hip_runtime.h>

#define N_NODES 8192
#define T_TYPES 8
#define HIN 256     // H*IN
#define OUTF 64
#define G3 192      // 3*OUT
#define BM 32       // nodes per block
#define CPT (N_NODES / BM)   // 256 chunks per type (worst case)

typedef __attribute__((ext_vector_type(8))) __bf16 bf16x8;
typedef __attribute__((ext_vector_type(4))) float f32x4;

// workspace byte offsets
#define WS_CURS 0
#define WS_PERM 256
#define WS_WAT  (256 + 262144)           // 8 types * 32768 B (bf16 [64][256], pre-swizzled)
#define WS_WIT  (WS_WAT + 262144)        // 8 types * 24576 B (bf16 [192][64], pre-swizzled)
#define WS_WHT  (WS_WIT + 196608)        // 8 types * 24576 B

// LDS byte offsets
#define L_XS  0        // [32][256] bf16, swizzled           16384
#define L_WAS 16384    // WaT[64][256] bf16, swizzled        32768
#define L_WIS 49152    // WiT[192][64] bf16, swizzled        24576
#define L_WHS 73728    // WhT[192][64] bf16, swizzled        24576
#define L_YS  98304    // [32][64] bf16, swizzled             4096
#define L_HS  102400   // [32][64] bf16, swizzled             4096
#define L_HF  106496   // [32][64] f32, plain                 8192
#define L_IDX 114688   // 32 ints                              128
#define L_TOT 114816

#define GLD_LDS16(g, l) __builtin_amdgcn_global_load_lds( \
    (const __attribute__((address_space(1))) void*)(g),   \
    (__attribute__((address_space(3))) void*)(l), 16, 0, 0)

__device__ __forceinline__ unsigned short f2bf(float f) {
    unsigned u = __float_as_uint(f);
    return (unsigned short)((u + 0x7FFFu + ((u >> 16) & 1u)) >> 16);
}
__device__ __forceinline__ int pack2bf(float a, float b) {
    return (int)f2bf(a) | ((int)f2bf(b) << 16);
}

// Transpose + bf16-convert + pre-swizzle all weights into d_ws; also zero cursors.
// Swizzle: lds byte address b within a row of stride S gets data from plain
// offset (b ^ ((row&7)<<4)), so a later ds_read_b128 at (row*S + 2k)^((row&7)<<4)
// returns W^T[row][k..k+7] conflict-free.
__global__ __launch_bounds__(256) void prep_weights(
    const float* __restrict__ W_att, const float* __restrict__ W_in,
    const float* __restrict__ W_hid, int* __restrict__ cursors,
    unsigned short* __restrict__ waT, unsigned short* __restrict__ wiT,
    unsigned short* __restrict__ whT)
{
    int i = blockIdx.x * 256 + threadIdx.x;
    if (i < 16) cursors[i] = 0;
    if (i < 131072) {                       // WaT: [t][col=64][k=256]
        int t = i >> 14;
        int A = (i & 16383) << 1;           // byte within 32KB tile
        int r = A >> 9;                     // col of W_att (row of W^T)
        int k = ((A & 511) ^ ((r & 7) << 4)) >> 1;
        waT[i] = f2bf(W_att[(((t << 8) + k) << 6) + r]);
    } else if (i < 229376) {                // WiT: [t][n=192][k=64]
        int j = i - 131072;
        int t = j / 12288;
        int f = j - t * 12288;
        int A = f << 1;
        int r = A >> 7;
        int k = ((A & 127) ^ ((r & 7) << 4)) >> 1;
        wiT[j] = f2bf(W_in[(t * 64 + k) * 192 + r]);
    } else if (i < 327680) {                // WhT
        int j = i - 229376;
        int t = j / 12288;
        int f = j - t * 12288;
        int A = f << 1;
        int r = A >> 7;
        int k = ((A & 127) ^ ((r & 7) << 4)) >> 1;
        whT[j] = f2bf(W_hid[(t * 64 + k) * 192 + r]);
    }
}

__global__ __launch_bounds__(256) void scatter_by_type(const int* __restrict__ nt,
                                                       int* __restrict__ cursors,
                                                       int* __restrict__ perm) {
    int i = blockIdx.x * 256 + threadIdx.x;
    int lane = threadIdx.x & 63;
    int t = nt[i];
    unsigned long long below = (1ull << lane) - 1ull;
    #pragma unroll
    for (int tt = 0; tt < T_TYPES; ++tt) {
        bool mine = (t == tt);
        unsigned long long mask = __ballot(mine);
        if (mask == 0ull) continue;
        int leader = __ffsll(mask) - 1;
        int cnt = __popcll(mask);
        int base = 0;
        if (lane == leader) base = atomicAdd(&cursors[tt], cnt);
        base = __shfl(base, leader, 64);
        if (mine) perm[tt * N_NODES + base + __popcll(mask & below)] = i;
    }
}

__global__ __launch_bounds__(256) void fused_rgnn(
    const float* __restrict__ agg, const float* __restrict__ h,
    const int* __restrict__ cursors, const int* __restrict__ perm,
    const unsigned short* __restrict__ waT, const unsigned short* __restrict__ wiT,
    const unsigned short* __restrict__ whT,
    const float* __restrict__ b_att, const float* __restrict__ b_in,
    const float* __restrict__ b_hid, float* __restrict__ out)
{
    __shared__ __align__(16) char smem[L_TOT];
    char* sm = smem;

    const int tid = threadIdx.x;
    const int t = blockIdx.x >> 8;        // CPT == 256
    const int chunk = blockIdx.x & 255;
    const int cnt = cursors[t];
    const int m0 = chunk * BM;
    if (m0 >= cnt) return;
    const int mcnt = min(BM, cnt - m0);

    const int lane = tid & 63;
    const int w = tid >> 6;               // wave id: owns output cols 16w..16w+15
    const int lr = lane & 15;
    const int lk = lane >> 4;
    const int col = (w << 4) + lr;
    const int swzA = (lr & 7) << 4;

    // Biases (independent loads, issued early).
    const float ba  = b_att[(t << 6) + col];
    const float bir = b_in [t * G3 + col];
    const float biz = b_in [t * G3 + 64 + col];
    const float bnn = b_in [t * G3 + 128 + col];
    const float bhr = b_hid[t * G3 + col];
    const float bhz = b_hid[t * G3 + 64 + col];
    const float bhn = b_hid[t * G3 + 128 + col];

    // --- per-thread perm gathers (no barrier needed) ---
    const int nb = tid >> 5;              // X: node base, covers 4 nodes nb+8s
    const int kx = (tid & 31) << 3;       // 8 floats of the 256-wide row
    int xg[4];
    #pragma unroll
    for (int s = 0; s < 4; ++s) {
        int node = nb + (s << 3);
        xg[s] = (node < mcnt) ? perm[t * N_NODES + m0 + node] : -1;
    }
    const int nh = tid >> 3;              // H: node, 8 threads per node
    const int kh = (tid & 7) << 3;
    int hg = (nh < mcnt) ? perm[t * N_NODES + m0 + nh] : -1;

    // --- issue X/H f32 loads ---
    float4 xv[4][2];
    #pragma unroll
    for (int s = 0; s < 4; ++s) {
        if (xg[s] >= 0) {
            const float* p = agg + (size_t)xg[s] * HIN + kx;
            xv[s][0] = *(const float4*)p;
            xv[s][1] = *(const float4*)(p + 4);
        } else {
            xv[s][0] = make_float4(0.f, 0.f, 0.f, 0.f);
            xv[s][1] = make_float4(0.f, 0.f, 0.f, 0.f);
        }
    }
    float4 hv0, hv1;
    if (hg >= 0) {
        const float* p = h + (size_t)hg * OUTF + kh;
        hv0 = *(const float4*)p;
        hv1 = *(const float4*)(p + 4);
    } else {
        hv0 = make_float4(0.f, 0.f, 0.f, 0.f);
        hv1 = make_float4(0.f, 0.f, 0.f, 0.f);
    }

    // --- issue weight global->LDS DMA (20 x 16B/lane, stays in flight) ---
    {
        const char* was = (const char*)(waT + (size_t)t * 16384);
        const char* wis = (const char*)(wiT + (size_t)t * 12288);
        const char* whs = (const char*)(whT + (size_t)t * 12288);
        #pragma unroll
        for (int r = 0; r < 8; ++r) {     // 32KB = 32 x 1KB chunks
            int c = (r << 2) + w;
            GLD_LDS16(was + (c << 10) + (lane << 4), sm + L_WAS + (c << 10));
        }
        #pragma unroll
        for (int r = 0; r < 6; ++r) {     // 24KB = 24 x 1KB chunks
            int c = (r << 2) + w;
            GLD_LDS16(wis + (c << 10) + (lane << 4), sm + L_WIS + (c << 10));
            GLD_LDS16(whs + (c << 10) + (lane << 4), sm + L_WHS + (c << 10));
        }
    }

    // --- consume X: relu -> bf16 -> swizzled LDS ---
    #pragma unroll
    for (int s = 0; s < 4; ++s) {
        int node = nb + (s << 3);
        float4 a = xv[s][0], b = xv[s][1];
        int4 wv;
        wv.x = pack2bf(fmaxf(a.x, 0.f), fmaxf(a.y, 0.f));
        wv.y = pack2bf(fmaxf(a.z, 0.f), fmaxf(a.w, 0.f));
        wv.z = pack2bf(fmaxf(b.x, 0.f), fmaxf(b.y, 0.f));
        wv.w = pack2bf(fmaxf(b.z, 0.f), fmaxf(b.w, 0.f));
        *(int4*)(sm + L_XS + (node << 9) + (((kx << 1)) ^ ((node & 7) << 4))) = wv;
    }
    // --- consume H: f32 copy + bf16 swizzled ---
    {
        *(float4*)(sm + L_HF + (nh << 8) + (kh << 2)) = hv0;
        *(float4*)(sm + L_HF + (nh << 8) + (kh << 2) + 16) = hv1;
        int4 wv;
        wv.x = pack2bf(hv0.x, hv0.y);
        wv.y = pack2bf(hv0.z, hv0.w);
        wv.z = pack2bf(hv1.x, hv1.y);
        wv.w = pack2bf(hv1.z, hv1.w);
        *(int4*)(sm + L_HS + (nh << 7) + ((kh << 1) ^ ((nh & 7) << 4))) = wv;
        if ((tid & 7) == 0) ((int*)(sm + L_IDX))[nh] = hg;
    }
    __syncthreads();   // drains weight DMA + LDS writes

    // --- phase 2: Y = relu(X @ Wa + ba), two 16x16 tiles per wave ---
    f32x4 acc0 = {0.f, 0.f, 0.f, 0.f}, acc1 = {0.f, 0.f, 0.f, 0.f};
    #pragma unroll
    for (int ks = 0; ks < 8; ++ks) {
        int koffB = (ks << 6) + (lk << 4);
        int off = koffB ^ swzA;
        bf16x8 b  = *(const bf16x8*)(sm + L_WAS + (((w << 4) + lr) << 9) + off);
        bf16x8 a0 = *(const bf16x8*)(sm + L_XS + (lr << 9) + off);
        bf16x8 a1 = *(const bf16x8*)(sm + L_XS + ((16 + lr) << 9) + off);
        acc0 = __builtin_amdgcn_mfma_f32_16x16x32_bf16(a0, b, acc0, 0, 0, 0);
        acc1 = __builtin_amdgcn_mfma_f32_16x16x32_bf16(a1, b, acc1, 0, 0, 0);
    }
    #pragma unroll
    for (int m = 0; m < 2; ++m) {
        #pragma unroll
        for (int r = 0; r < 4; ++r) {
            int row = (m << 4) + (lk << 2) + r;
            float y = fmaxf((m ? acc1[r] : acc0[r]) + ba, 0.f);
            *(unsigned short*)(sm + L_YS + (row << 7) +
                               (((col << 1)) ^ ((row & 7) << 4))) = f2bf(y);
        }
    }
    __syncthreads();

    // --- phase 3: gi = Y @ Wi, gh = H @ Wh; wave w owns gate cols 16w (r,z,n) ---
    f32x4 gi[2][3], gh[2][3];
    #pragma unroll
    for (int m = 0; m < 2; ++m)
        #pragma unroll
        for (int g = 0; g < 3; ++g) {
            gi[m][g] = (f32x4){0.f, 0.f, 0.f, 0.f};
            gh[m][g] = (f32x4){0.f, 0.f, 0.f, 0.f};
        }
    #pragma unroll
    for (int ks = 0; ks < 2; ++ks) {
        int off = ((ks << 6) + (lk << 4)) ^ swzA;
        bf16x8 ay0 = *(const bf16x8*)(sm + L_YS + (lr << 7) + off);
        bf16x8 ay1 = *(const bf16x8*)(sm + L_YS + ((16 + lr) << 7) + off);
        bf16x8 ah0 = *(const bf16x8*)(sm + L_HS + (lr << 7) + off);
        bf16x8 ah1 = *(const bf16x8*)(sm + L_HS + ((16 + lr) << 7) + off);
        #pragma unroll
        for (int g = 0; g < 3; ++g) {
            int brow = (g << 6) + col;
            bf16x8 bi = *(const bf16x8*)(sm + L_WIS + (brow << 7) + off);
            bf16x8 bh = *(const bf16x8*)(sm + L_WHS + (brow << 7) + off);
            gi[0][g] = __builtin_amdgcn_mfma_f32_16x16x32_bf16(ay0, bi, gi[0][g], 0, 0, 0);
            gi[1][g] = __builtin_amdgcn_mfma_f32_16x16x32_bf16(ay1, bi, gi[1][g], 0, 0, 0);
            gh[0][g] = __builtin_amdgcn_mfma_f32_16x16x32_bf16(ah0, bh, gh[0][g], 0, 0, 0);
            gh[1][g] = __builtin_amdgcn_mfma_f32_16x16x32_bf16(ah1, bh, gh[1][g], 0, 0, 0);
        }
    }

    // --- epilogue: GRU gates (f32) + scatter store ---
    const int* idxp = (const int*)(sm + L_IDX);
    #pragma unroll
    for (int m = 0; m < 2; ++m) {
        #pragma unroll
        for (int r = 0; r < 4; ++r) {
            int node = (m << 4) + (lk << 2) + r;
            if (node < mcnt) {
                float rv = gi[m][0][r] + bir + gh[m][0][r] + bhr;
                float rg = 1.f / (1.f + __expf(-rv));
                float zv = gi[m][1][r] + biz + gh[m][1][r] + bhz;
                float zg = 1.f / (1.f + __expf(-zv));
                float ng = tanhf(gi[m][2][r] + bnn + rg * (gh[m][2][r] + bhn));
                float hold = *(const float*)(sm + L_HF + (node << 8) + (col << 2));
                out[(size_t)idxp[node] * OUTF + col] = (1.f - zg) * ng + zg * hold;
            }
        }
    }
}

extern "C" void kernel_launch(void* const* d_in, const int* in_sizes, int n_in,
                              void* d_out, int out_size, void* d_ws, size_t ws_size,
                              hipStream_t stream) {
    const float* agg   = (const float*)d_in[0];
    const float* h     = (const float*)d_in[1];
    const int*   ntype = (const int*)d_in[2];
    const float* W_att = (const float*)d_in[3];
    const float* b_att = (const float*)d_in[4];
    const float* W_in  = (const float*)d_in[5];
    const float* W_hid = (const float*)d_in[6];
    const float* b_in  = (const float*)d_in[7];
    const float* b_hid = (const float*)d_in[8];
    float* out = (float*)d_out;

    char* ws = (char*)d_ws;
    int* cursors = (int*)(ws + WS_CURS);
    int* perm = (int*)(ws + WS_PERM);
    unsigned short* waT = (unsigned short*)(ws + WS_WAT);
    unsigned short* wiT = (unsigned short*)(ws + WS_WIT);
    unsigned short* whT = (unsigned short*)(ws + WS_WHT);

    prep_weights<<<1280, 256, 0, stream>>>(W_att, W_in, W_hid, cursors, waT, wiT, whT);
    scatter_by_type<<<N_NODES / 256, 256, 0, stream>>>(ntype, cursors, perm);
    fused_rgnn<<<T_TYPES * CPT, 256, 0, stream>>>(agg, h, cursors, perm,
        waT, wiT, whT, b_att, b_in, b_hid, out);
}

// Round 4
// 36.771 us; speedup vs baseline: 1.8255x; 1.0059x over previous
//
#include <hip/hip_runtime.h>

#define N_NODES 8192
#define T_TYPES 8
#define HIN 256     // H*IN
#define OUTF 64
#define G3 192      // 3*OUT
#define BM 32       // nodes per block
#define CPT (N_NODES / BM)   // 256 chunks per type (worst case)

typedef __attribute__((ext_vector_type(8))) __bf16 bf16x8;
typedef __attribute__((ext_vector_type(4))) float f32x4;

// workspace byte offsets
#define WS_CURS 0
#define WS_PERM 256
#define WS_WAT  (256 + 262144)           // 8 types * 32768 B (bf16 [64][256], pre-swizzled)
#define WS_WIT  (WS_WAT + 262144)        // 8 types * 24576 B (bf16 [192][64], pre-swizzled)
#define WS_WHT  (WS_WIT + 196608)        // 8 types * 24576 B

// LDS byte offsets (fused kernel)
#define L_XS  0        // [32][256] bf16, swizzled           16384
#define L_WAS 16384    // WaT[64][256] bf16, swizzled        32768
#define L_WIS 49152    // WiT[192][64] bf16, swizzled        24576
#define L_WHS 73728    // WhT[192][64] bf16, swizzled        24576
#define L_YS  98304    // [32][64] bf16, swizzled             4096
#define L_HS  102400   // [32][64] bf16, swizzled             4096
#define L_HF  106496   // [32][64] f32, plain                 8192
#define L_IDX 114688   // 32 ints                              128
#define L_TOT 114816

#define GLD_LDS16(g, l) __builtin_amdgcn_global_load_lds( \
    (const __attribute__((address_space(1))) void*)(g),   \
    (__attribute__((address_space(3))) void*)(l), 16, 0, 0)

__device__ __forceinline__ unsigned short f2bf(float f) {
    unsigned u = __float_as_uint(f);
    return (unsigned short)((u + 0x7FFFu + ((u >> 16) & 1u)) >> 16);
}
__device__ __forceinline__ int pack2bf(float a, float b) {
    return (int)f2bf(a) | ((int)f2bf(b) << 16);
}

// Coalesced LDS-staged transpose + bf16 convert + pre-swizzle of all weights.
// 80 blocks: b<32 -> W_att (t=b>>2, k-tile kt=b&3, 64x64 f32 tile);
// b in [32,56) -> W_in (t=j/3, n-tile nt=j%3, 64k x 64n tile);
// b in [56,80) -> W_hid likewise.
// Output layout (unchanged from R3): row r of W^T at byte r*rowBytes; within the
// row, plain byte p (p = k*2) stored at p ^ ((r&7)<<4)  (XOR within low 7 bits).
__global__ __launch_bounds__(256) void prep_weights(
    const float* __restrict__ W_att, const float* __restrict__ W_in,
    const float* __restrict__ W_hid, int* __restrict__ cursors,
    unsigned short* __restrict__ waT, unsigned short* __restrict__ wiT,
    unsigned short* __restrict__ whT)
{
    __shared__ float Lf[64][68];   // [kk][r_local], padded
    const int tid = threadIdx.x;
    const int b = blockIdx.x;
    if (b == 0 && tid < 16) cursors[tid] = 0;

    const float* src;
    unsigned short* dstBase;
    int srcStride, rowBytes, colBase, rBase;

    if (b < 32) {
        int t = b >> 2, kt = b & 3;
        src = W_att + (((size_t)t * 256 + kt * 64) << 6);
        srcStride = 64;
        dstBase = waT + (size_t)t * 16384;
        rowBytes = 512; colBase = kt * 128; rBase = 0;
    } else {
        int j = b - 32;
        int isWh = (j >= 24); if (isWh) j -= 24;
        int t = j / 3, nt = j - t * 3;
        src = (isWh ? W_hid : W_in) + (size_t)t * 64 * 192 + nt * 64;
        srcStride = 192;
        dstBase = (isWh ? whT : wiT) + (size_t)t * 12288;
        rowBytes = 128; colBase = 0; rBase = nt * 64;
    }

    // Coalesced loads: per instruction, 64 lanes read 64 consecutive float4.
    #pragma unroll
    for (int e = 0; e < 4; ++e) {
        int f = e * 256 + tid;            // float4 index within the 64x64 tile
        int kk = f >> 4, c = (f & 15) << 2;
        float4 v = *(const float4*)(src + kk * srcStride + c);
        Lf[kk][c] = v.x; Lf[kk][c + 1] = v.y; Lf[kk][c + 2] = v.z; Lf[kk][c + 3] = v.w;
    }
    __syncthreads();

    // Emit: 512 int4 per tile (2 per thread); lane -> r varies (LDS 2-way max).
    #pragma unroll
    for (int e = 0; e < 2; ++e) {
        int q = e * 256 + tid;
        int ko8 = q >> 6, rl = q & 63;
        int r = rBase + rl;
        unsigned short tmp[8];
        #pragma unroll
        for (int j2 = 0; j2 < 8; ++j2)
            tmp[j2] = f2bf(Lf[ko8 * 8 + j2][rl]);
        int4 wv;
        wv.x = (int)tmp[0] | ((int)tmp[1] << 16);
        wv.y = (int)tmp[2] | ((int)tmp[3] << 16);
        wv.z = (int)tmp[4] | ((int)tmp[5] << 16);
        wv.w = (int)tmp[6] | ((int)tmp[7] << 16);
        int B = r * rowBytes + colBase + ((ko8 << 4) ^ ((r & 7) << 4));
        *(int4*)((char*)dstBase + B) = wv;
    }
}

__global__ __launch_bounds__(256) void scatter_by_type(const int* __restrict__ nt,
                                                       int* __restrict__ cursors,
                                                       int* __restrict__ perm) {
    int i = blockIdx.x * 256 + threadIdx.x;
    int lane = threadIdx.x & 63;
    int t = nt[i];
    unsigned long long below = (1ull << lane) - 1ull;
    #pragma unroll
    for (int tt = 0; tt < T_TYPES; ++tt) {
        bool mine = (t == tt);
        unsigned long long mask = __ballot(mine);
        if (mask == 0ull) continue;
        int leader = __ffsll(mask) - 1;
        int cnt = __popcll(mask);
        int base = 0;
        if (lane == leader) base = atomicAdd(&cursors[tt], cnt);
        base = __shfl(base, leader, 64);
        if (mine) perm[tt * N_NODES + base + __popcll(mask & below)] = i;
    }
}

__global__ __launch_bounds__(256) void fused_rgnn(
    const float* __restrict__ agg, const float* __restrict__ h,
    const int* __restrict__ cursors, const int* __restrict__ perm,
    const unsigned short* __restrict__ waT, const unsigned short* __restrict__ wiT,
    const unsigned short* __restrict__ whT,
    const float* __restrict__ b_att, const float* __restrict__ b_in,
    const float* __restrict__ b_hid, float* __restrict__ out)
{
    __shared__ __align__(16) char smem[L_TOT];
    char* sm = smem;

    const int tid = threadIdx.x;
    const int t = blockIdx.x >> 8;        // CPT == 256
    const int chunk = blockIdx.x & 255;
    const int cnt = cursors[t];
    const int m0 = chunk * BM;
    if (m0 >= cnt) return;
    const int mcnt = min(BM, cnt - m0);

    const int lane = tid & 63;
    const int w = tid >> 6;               // wave id: owns output cols 16w..16w+15
    const int lr = lane & 15;
    const int lk = lane >> 4;
    const int col = (w << 4) + lr;
    const int swzA = (lr & 7) << 4;

    // Biases (independent loads, issued early).
    const float ba  = b_att[(t << 6) + col];
    const float bir = b_in [t * G3 + col];
    const float biz = b_in [t * G3 + 64 + col];
    const float bnn = b_in [t * G3 + 128 + col];
    const float bhr = b_hid[t * G3 + col];
    const float bhz = b_hid[t * G3 + 64 + col];
    const float bhn = b_hid[t * G3 + 128 + col];

    // --- per-thread perm gathers (no barrier needed) ---
    const int nb = tid >> 5;              // X: node base, covers 4 nodes nb+8s
    const int kx = (tid & 31) << 3;       // 8 floats of the 256-wide row
    int xg[4];
    #pragma unroll
    for (int s = 0; s < 4; ++s) {
        int node = nb + (s << 3);
        xg[s] = (node < mcnt) ? perm[t * N_NODES + m0 + node] : -1;
    }
    const int nh = tid >> 3;              // H: node, 8 threads per node
    const int kh = (tid & 7) << 3;
    int hg = (nh < mcnt) ? perm[t * N_NODES + m0 + nh] : -1;

    // --- issue X/H f32 loads ---
    float4 xv[4][2];
    #pragma unroll
    for (int s = 0; s < 4; ++s) {
        if (xg[s] >= 0) {
            const float* p = agg + (size_t)xg[s] * HIN + kx;
            xv[s][0] = *(const float4*)p;
            xv[s][1] = *(const float4*)(p + 4);
        } else {
            xv[s][0] = make_float4(0.f, 0.f, 0.f, 0.f);
            xv[s][1] = make_float4(0.f, 0.f, 0.f, 0.f);
        }
    }
    float4 hv0, hv1;
    if (hg >= 0) {
        const float* p = h + (size_t)hg * OUTF + kh;
        hv0 = *(const float4*)p;
        hv1 = *(const float4*)(p + 4);
    } else {
        hv0 = make_float4(0.f, 0.f, 0.f, 0.f);
        hv1 = make_float4(0.f, 0.f, 0.f, 0.f);
    }

    // --- issue weight global->LDS DMA (20 x 16B/lane, stays in flight) ---
    {
        const char* was = (const char*)(waT + (size_t)t * 16384);
        const char* wis = (const char*)(wiT + (size_t)t * 12288);
        const char* whs = (const char*)(whT + (size_t)t * 12288);
        #pragma unroll
        for (int r = 0; r < 8; ++r) {     // 32KB = 32 x 1KB chunks
            int c = (r << 2) + w;
            GLD_LDS16(was + (c << 10) + (lane << 4), sm + L_WAS + (c << 10));
        }
        #pragma unroll
        for (int r = 0; r < 6; ++r) {     // 24KB = 24 x 1KB chunks
            int c = (r << 2) + w;
            GLD_LDS16(wis + (c << 10) + (lane << 4), sm + L_WIS + (c << 10));
            GLD_LDS16(whs + (c << 10) + (lane << 4), sm + L_WHS + (c << 10));
        }
    }

    // --- consume X: relu -> bf16 -> swizzled LDS ---
    #pragma unroll
    for (int s = 0; s < 4; ++s) {
        int node = nb + (s << 3);
        float4 a = xv[s][0], b = xv[s][1];
        int4 wv;
        wv.x = pack2bf(fmaxf(a.x, 0.f), fmaxf(a.y, 0.f));
        wv.y = pack2bf(fmaxf(a.z, 0.f), fmaxf(a.w, 0.f));
        wv.z = pack2bf(fmaxf(b.x, 0.f), fmaxf(b.y, 0.f));
        wv.w = pack2bf(fmaxf(b.z, 0.f), fmaxf(b.w, 0.f));
        *(int4*)(sm + L_XS + (node << 9) + (((kx << 1)) ^ ((node & 7) << 4))) = wv;
    }
    // --- consume H: f32 copy + bf16 swizzled ---
    {
        *(float4*)(sm + L_HF + (nh << 8) + (kh << 2)) = hv0;
        *(float4*)(sm + L_HF + (nh << 8) + (kh << 2) + 16) = hv1;
        int4 wv;
        wv.x = pack2bf(hv0.x, hv0.y);
        wv.y = pack2bf(hv0.z, hv0.w);
        wv.z = pack2bf(hv1.x, hv1.y);
        wv.w = pack2bf(hv1.z, hv1.w);
        *(int4*)(sm + L_HS + (nh << 7) + ((kh << 1) ^ ((nh & 7) << 4))) = wv;
        if ((tid & 7) == 0) ((int*)(sm + L_IDX))[nh] = hg;
    }
    __syncthreads();   // drains weight DMA + LDS writes

    // --- phase 2: Y = relu(X @ Wa + ba), two 16x16 tiles per wave ---
    f32x4 acc0 = {0.f, 0.f, 0.f, 0.f}, acc1 = {0.f, 0.f, 0.f, 0.f};
    #pragma unroll
    for (int ks = 0; ks < 8; ++ks) {
        int koffB = (ks << 6) + (lk << 4);
        int off = koffB ^ swzA;
        bf16x8 b  = *(const bf16x8*)(sm + L_WAS + (((w << 4) + lr) << 9) + off);
        bf16x8 a0 = *(const bf16x8*)(sm + L_XS + (lr << 9) + off);
        bf16x8 a1 = *(const bf16x8*)(sm + L_XS + ((16 + lr) << 9) + off);
        acc0 = __builtin_amdgcn_mfma_f32_16x16x32_bf16(a0, b, acc0, 0, 0, 0);
        acc1 = __builtin_amdgcn_mfma_f32_16x16x32_bf16(a1, b, acc1, 0, 0, 0);
    }
    #pragma unroll
    for (int m = 0; m < 2; ++m) {
        #pragma unroll
        for (int r = 0; r < 4; ++r) {
            int row = (m << 4) + (lk << 2) + r;
            float y = fmaxf((m ? acc1[r] : acc0[r]) + ba, 0.f);
            *(unsigned short*)(sm + L_YS + (row << 7) +
                               (((col << 1)) ^ ((row & 7) << 4))) = f2bf(y);
        }
    }
    __syncthreads();

    // --- phase 3: gi = Y @ Wi, gh = H @ Wh; wave w owns gate cols 16w (r,z,n) ---
    f32x4 gi[2][3], gh[2][3];
    #pragma unroll
    for (int m = 0; m < 2; ++m)
        #pragma unroll
        for (int g = 0; g < 3; ++g) {
            gi[m][g] = (f32x4){0.f, 0.f, 0.f, 0.f};
            gh[m][g] = (f32x4){0.f, 0.f, 0.f, 0.f};
        }
    #pragma unroll
    for (int ks = 0; ks < 2; ++ks) {
        int off = ((ks << 6) + (lk << 4)) ^ swzA;
        bf16x8 ay0 = *(const bf16x8*)(sm + L_YS + (lr << 7) + off);
        bf16x8 ay1 = *(const bf16x8*)(sm + L_YS + ((16 + lr) << 7) + off);
        bf16x8 ah0 = *(const bf16x8*)(sm + L_HS + (lr << 7) + off);
        bf16x8 ah1 = *(const bf16x8*)(sm + L_HS + ((16 + lr) << 7) + off);
        #pragma unroll
        for (int g = 0; g < 3; ++g) {
            int brow = (g << 6) + col;
            bf16x8 bi = *(const bf16x8*)(sm + L_WIS + (brow << 7) + off);
            bf16x8 bh = *(const bf16x8*)(sm + L_WHS + (brow << 7) + off);
            gi[0][g] = __builtin_amdgcn_mfma_f32_16x16x32_bf16(ay0, bi, gi[0][g], 0, 0, 0);
            gi[1][g] = __builtin_amdgcn_mfma_f32_16x16x32_bf16(ay1, bi, gi[1][g], 0, 0, 0);
            gh[0][g] = __builtin_amdgcn_mfma_f32_16x16x32_bf16(ah0, bh, gh[0][g], 0, 0, 0);
            gh[1][g] = __builtin_amdgcn_mfma_f32_16x16x32_bf16(ah1, bh, gh[1][g], 0, 0, 0);
        }
    }

    // --- epilogue: GRU gates (f32) + scatter store ---
    const int* idxp = (const int*)(sm + L_IDX);
    #pragma unroll
    for (int m = 0; m < 2; ++m) {
        #pragma unroll
        for (int r = 0; r < 4; ++r) {
            int node = (m << 4) + (lk << 2) + r;
            if (node < mcnt) {
                float rv = gi[m][0][r] + bir + gh[m][0][r] + bhr;
                float rg = 1.f / (1.f + __expf(-rv));
                float zv = gi[m][1][r] + biz + gh[m][1][r] + bhz;
                float zg = 1.f / (1.f + __expf(-zv));
                float ng = tanhf(gi[m][2][r] + bnn + rg * (gh[m][2][r] + bhn));
                float hold = *(const float*)(sm + L_HF + (node << 8) + (col << 2));
                out[(size_t)idxp[node] * OUTF + col] = (1.f - zg) * ng + zg * hold;
            }
        }
    }
}

extern "C" void kernel_launch(void* const* d_in, const int* in_sizes, int n_in,
                              void* d_out, int out_size, void* d_ws, size_t ws_size,
                              hipStream_t stream) {
    const float* agg   = (const float*)d_in[0];
    const float* h     = (const float*)d_in[1];
    const int*   ntype = (const int*)d_in[2];
    const float* W_att = (const float*)d_in[3];
    const float* b_att = (const float*)d_in[4];
    const float* W_in  = (const float*)d_in[5];
    const float* W_hid = (const float*)d_in[6];
    const float* b_in  = (const float*)d_in[7];
    const float* b_hid = (const float*)d_in[8];
    float* out = (float*)d_out;

    char* ws = (char*)d_ws;
    int* cursors = (int*)(ws + WS_CURS);
    int* perm = (int*)(ws + WS_PERM);
    unsigned short* waT = (unsigned short*)(ws + WS_WAT);
    unsigned short* wiT = (unsigned short*)(ws + WS_WIT);
    unsigned short* whT = (unsigned short*)(ws + WS_WHT);

    prep_weights<<<80, 256, 0, stream>>>(W_att, W_in, W_hid, cursors, waT, wiT, whT);
    scatter_by_type<<<N_NODES / 256, 256, 0, stream>>>(ntype, cursors, perm);
    fused_rgnn<<<T_TYPES * CPT, 256, 0, stream>>>(agg, h, cursors, perm,
        waT, wiT, whT, b_att, b_in, b_hid, out);
}

// Round 5
// 36.631 us; speedup vs baseline: 1.8324x; 1.0038x over previous
//
#include <hip/hip_runtime.h>

#define N_NODES 8192
#define T_TYPES 8
#define HIN 256     // H*IN
#define OUTF 64
#define G3 192      // 3*OUT
#define BM 32       // nodes per block
#define MAXBLK 264  // max total chunks = 8192/32 + 7 partials = 263

typedef __attribute__((ext_vector_type(8))) __bf16 bf16x8;
typedef __attribute__((ext_vector_type(4))) float f32x4;

// workspace byte offsets
#define WS_CURS 0
#define WS_PERM 256
#define WS_WAT  (256 + 262144)           // 8 types * 32768 B (bf16 [64][256], pre-swizzled)
#define WS_WIT  (WS_WAT + 262144)        // 8 types * 24576 B (bf16 [192][64], pre-swizzled)
#define WS_WHT  (WS_WIT + 196608)        // 8 types * 24576 B

// LDS byte offsets (fused kernel)
#define L_XS  0        // [32][256] bf16, swizzled           16384
#define L_WAS 16384    // WaT[64][256] bf16, swizzled        32768
#define L_WIS 49152    // WiT[192][64] bf16, swizzled        24576
#define L_WHS 73728    // WhT[192][64] bf16, swizzled        24576
#define L_YS  98304    // [32][64] bf16, swizzled             4096
#define L_HS  102400   // [32][64] bf16, swizzled             4096
#define L_HF  106496   // [32][64] f32, plain                 8192
#define L_IDX 114688   // 32 ints                              128
#define L_TOT 114816

#define GLD_LDS16(g, l) __builtin_amdgcn_global_load_lds( \
    (const __attribute__((address_space(1))) void*)(g),   \
    (__attribute__((address_space(3))) void*)(l), 16, 0, 0)

__device__ __forceinline__ unsigned short f2bf(float f) {
    unsigned u = __float_as_uint(f);
    return (unsigned short)((u + 0x7FFFu + ((u >> 16) & 1u)) >> 16);
}
__device__ __forceinline__ int pack2bf(float a, float b) {
    return (int)f2bf(a) | ((int)f2bf(b) << 16);
}

// Coalesced LDS-staged transpose + bf16 convert + pre-swizzle of all weights.
__global__ __launch_bounds__(256) void prep_weights(
    const float* __restrict__ W_att, const float* __restrict__ W_in,
    const float* __restrict__ W_hid, int* __restrict__ cursors,
    unsigned short* __restrict__ waT, unsigned short* __restrict__ wiT,
    unsigned short* __restrict__ whT)
{
    __shared__ float Lf[64][68];   // [kk][r_local], padded
    const int tid = threadIdx.x;
    const int b = blockIdx.x;
    if (b == 0 && tid < 16) cursors[tid] = 0;

    const float* src;
    unsigned short* dstBase;
    int srcStride, rowBytes, colBase, rBase;

    if (b < 32) {
        int t = b >> 2, kt = b & 3;
        src = W_att + (((size_t)t * 256 + kt * 64) << 6);
        srcStride = 64;
        dstBase = waT + (size_t)t * 16384;
        rowBytes = 512; colBase = kt * 128; rBase = 0;
    } else {
        int j = b - 32;
        int isWh = (j >= 24); if (isWh) j -= 24;
        int t = j / 3, nt = j - t * 3;
        src = (isWh ? W_hid : W_in) + (size_t)t * 64 * 192 + nt * 64;
        srcStride = 192;
        dstBase = (isWh ? whT : wiT) + (size_t)t * 12288;
        rowBytes = 128; colBase = 0; rBase = nt * 64;
    }

    #pragma unroll
    for (int e = 0; e < 4; ++e) {
        int f = e * 256 + tid;            // float4 index within the 64x64 tile
        int kk = f >> 4, c = (f & 15) << 2;
        float4 v = *(const float4*)(src + kk * srcStride + c);
        Lf[kk][c] = v.x; Lf[kk][c + 1] = v.y; Lf[kk][c + 2] = v.z; Lf[kk][c + 3] = v.w;
    }
    __syncthreads();

    #pragma unroll
    for (int e = 0; e < 2; ++e) {
        int q = e * 256 + tid;
        int ko8 = q >> 6, rl = q & 63;
        int r = rBase + rl;
        unsigned short tmp[8];
        #pragma unroll
        for (int j2 = 0; j2 < 8; ++j2)
            tmp[j2] = f2bf(Lf[ko8 * 8 + j2][rl]);
        int4 wv;
        wv.x = (int)tmp[0] | ((int)tmp[1] << 16);
        wv.y = (int)tmp[2] | ((int)tmp[3] << 16);
        wv.z = (int)tmp[4] | ((int)tmp[5] << 16);
        wv.w = (int)tmp[6] | ((int)tmp[7] << 16);
        int B = r * rowBytes + colBase + ((ko8 << 4) ^ ((r & 7) << 4));
        *(int4*)((char*)dstBase + B) = wv;
    }
}

__global__ __launch_bounds__(256) void scatter_by_type(const int* __restrict__ nt,
                                                       int* __restrict__ cursors,
                                                       int* __restrict__ perm) {
    int i = blockIdx.x * 256 + threadIdx.x;
    int lane = threadIdx.x & 63;
    int t = nt[i];
    unsigned long long below = (1ull << lane) - 1ull;
    #pragma unroll
    for (int tt = 0; tt < T_TYPES; ++tt) {
        bool mine = (t == tt);
        unsigned long long mask = __ballot(mine);
        if (mask == 0ull) continue;
        int leader = __ffsll(mask) - 1;
        int cnt = __popcll(mask);
        int base = 0;
        if (lane == leader) base = atomicAdd(&cursors[tt], cnt);
        base = __shfl(base, leader, 64);
        if (mine) perm[tt * N_NODES + base + __popcll(mask & below)] = i;
    }
}

__global__ __launch_bounds__(256) void fused_rgnn(
    const float* __restrict__ agg, const float* __restrict__ h,
    const int* __restrict__ cursors, const int* __restrict__ perm,
    const unsigned short* __restrict__ waT, const unsigned short* __restrict__ wiT,
    const unsigned short* __restrict__ whT,
    const float* __restrict__ b_att, const float* __restrict__ b_in,
    const float* __restrict__ b_hid, float* __restrict__ out)
{
    __shared__ __align__(16) char smem[L_TOT];
    char* sm = smem;

    const int tid = threadIdx.x;
    const int b = blockIdx.x;

    // Derive (type, chunk) from the 8 counts: prefix scan over ceil(cnt/BM).
    const int4 c0 = *(const int4*)cursors;
    const int4 c1 = *(const int4*)(cursors + 4);
    const int cntArr[8] = {c0.x, c0.y, c0.z, c0.w, c1.x, c1.y, c1.z, c1.w};
    int t = -1, chunk = 0, cnt = 0, acc = 0;
    #pragma unroll
    for (int tt = 0; tt < T_TYPES; ++tt) {
        int nc = (cntArr[tt] + BM - 1) >> 5;
        if (t < 0 && b < acc + nc) { t = tt; chunk = b - acc; cnt = cntArr[tt]; }
        acc += nc;
    }
    if (t < 0) return;                     // at most 8 blocks exit
    const int m0 = chunk * BM;
    const int mcnt = min(BM, cnt - m0);

    const int lane = tid & 63;
    const int w = tid >> 6;               // wave id: owns output cols 16w..16w+15
    const int lr = lane & 15;
    const int lk = lane >> 4;
    const int col = (w << 4) + lr;
    const int swzA = (lr & 7) << 4;

    // Biases (independent loads, issued early).
    const float ba  = b_att[(t << 6) + col];
    const float bir = b_in [t * G3 + col];
    const float biz = b_in [t * G3 + 64 + col];
    const float bnn = b_in [t * G3 + 128 + col];
    const float bhr = b_hid[t * G3 + col];
    const float bhz = b_hid[t * G3 + 64 + col];
    const float bhn = b_hid[t * G3 + 128 + col];

    // --- per-thread perm gathers (no barrier needed) ---
    const int nb = tid >> 5;              // X: node base, covers 4 nodes nb+8s
    const int kx = (tid & 31) << 3;       // 8 floats of the 256-wide row
    int xg[4];
    #pragma unroll
    for (int s = 0; s < 4; ++s) {
        int node = nb + (s << 3);
        xg[s] = (node < mcnt) ? perm[t * N_NODES + m0 + node] : -1;
    }
    const int nh = tid >> 3;              // H: node, 8 threads per node
    const int kh = (tid & 7) << 3;
    int hg = (nh < mcnt) ? perm[t * N_NODES + m0 + nh] : -1;

    // --- issue X/H f32 loads ---
    float4 xv[4][2];
    #pragma unroll
    for (int s = 0; s < 4; ++s) {
        if (xg[s] >= 0) {
            const float* p = agg + (size_t)xg[s] * HIN + kx;
            xv[s][0] = *(const float4*)p;
            xv[s][1] = *(const float4*)(p + 4);
        } else {
            xv[s][0] = make_float4(0.f, 0.f, 0.f, 0.f);
            xv[s][1] = make_float4(0.f, 0.f, 0.f, 0.f);
        }
    }
    float4 hv0, hv1;
    if (hg >= 0) {
        const float* p = h + (size_t)hg * OUTF + kh;
        hv0 = *(const float4*)p;
        hv1 = *(const float4*)(p + 4);
    } else {
        hv0 = make_float4(0.f, 0.f, 0.f, 0.f);
        hv1 = make_float4(0.f, 0.f, 0.f, 0.f);
    }

    // --- issue weight global->LDS DMA (20 x 16B/lane, stays in flight) ---
    {
        const char* was = (const char*)(waT + (size_t)t * 16384);
        const char* wis = (const char*)(wiT + (size_t)t * 12288);
        const char* whs = (const char*)(whT + (size_t)t * 12288);
        #pragma unroll
        for (int r = 0; r < 8; ++r) {     // 32KB = 32 x 1KB chunks
            int c = (r << 2) + w;
            GLD_LDS16(was + (c << 10) + (lane << 4), sm + L_WAS + (c << 10));
        }
        #pragma unroll
        for (int r = 0; r < 6; ++r) {     // 24KB = 24 x 1KB chunks
            int c = (r << 2) + w;
            GLD_LDS16(wis + (c << 10) + (lane << 4), sm + L_WIS + (c << 10));
            GLD_LDS16(whs + (c << 10) + (lane << 4), sm + L_WHS + (c << 10));
        }
    }

    // --- consume X: relu -> bf16 -> swizzled LDS ---
    #pragma unroll
    for (int s = 0; s < 4; ++s) {
        int node = nb + (s << 3);
        float4 a = xv[s][0], bq = xv[s][1];
        int4 wv;
        wv.x = pack2bf(fmaxf(a.x, 0.f), fmaxf(a.y, 0.f));
        wv.y = pack2bf(fmaxf(a.z, 0.f), fmaxf(a.w, 0.f));
        wv.z = pack2bf(fmaxf(bq.x, 0.f), fmaxf(bq.y, 0.f));
        wv.w = pack2bf(fmaxf(bq.z, 0.f), fmaxf(bq.w, 0.f));
        *(int4*)(sm + L_XS + (node << 9) + (((kx << 1)) ^ ((node & 7) << 4))) = wv;
    }
    // --- consume H: f32 copy + bf16 swizzled ---
    {
        *(float4*)(sm + L_HF + (nh << 8) + (kh << 2)) = hv0;
        *(float4*)(sm + L_HF + (nh << 8) + (kh << 2) + 16) = hv1;
        int4 wv;
        wv.x = pack2bf(hv0.x, hv0.y);
        wv.y = pack2bf(hv0.z, hv0.w);
        wv.z = pack2bf(hv1.x, hv1.y);
        wv.w = pack2bf(hv1.z, hv1.w);
        *(int4*)(sm + L_HS + (nh << 7) + ((kh << 1) ^ ((nh & 7) << 4))) = wv;
        if ((tid & 7) == 0) ((int*)(sm + L_IDX))[nh] = hg;
    }
    __syncthreads();   // drains weight DMA + LDS writes

    // --- phase 2: Y = relu(X @ Wa + ba), two 16x16 tiles per wave ---
    f32x4 acc0 = {0.f, 0.f, 0.f, 0.f}, acc1 = {0.f, 0.f, 0.f, 0.f};
    #pragma unroll
    for (int ks = 0; ks < 8; ++ks) {
        int koffB = (ks << 6) + (lk << 4);
        int off = koffB ^ swzA;
        bf16x8 bb = *(const bf16x8*)(sm + L_WAS + (((w << 4) + lr) << 9) + off);
        bf16x8 a0 = *(const bf16x8*)(sm + L_XS + (lr << 9) + off);
        bf16x8 a1 = *(const bf16x8*)(sm + L_XS + ((16 + lr) << 9) + off);
        acc0 = __builtin_amdgcn_mfma_f32_16x16x32_bf16(a0, bb, acc0, 0, 0, 0);
        acc1 = __builtin_amdgcn_mfma_f32_16x16x32_bf16(a1, bb, acc1, 0, 0, 0);
    }
    #pragma unroll
    for (int m = 0; m < 2; ++m) {
        #pragma unroll
        for (int r = 0; r < 4; ++r) {
            int row = (m << 4) + (lk << 2) + r;
            float y = fmaxf((m ? acc1[r] : acc0[r]) + ba, 0.f);
            *(unsigned short*)(sm + L_YS + (row << 7) +
                               (((col << 1)) ^ ((row & 7) << 4))) = f2bf(y);
        }
    }
    __syncthreads();

    // --- phase 3: gi = Y @ Wi, gh = H @ Wh; wave w owns gate cols 16w (r,z,n) ---
    f32x4 gi[2][3], gh[2][3];
    #pragma unroll
    for (int m = 0; m < 2; ++m)
        #pragma unroll
        for (int g = 0; g < 3; ++g) {
            gi[m][g] = (f32x4){0.f, 0.f, 0.f, 0.f};
            gh[m][g] = (f32x4){0.f, 0.f, 0.f, 0.f};
        }
    #pragma unroll
    for (int ks = 0; ks < 2; ++ks) {
        int off = ((ks << 6) + (lk << 4)) ^ swzA;
        bf16x8 ay0 = *(const bf16x8*)(sm + L_YS + (lr << 7) + off);
        bf16x8 ay1 = *(const bf16x8*)(sm + L_YS + ((16 + lr) << 7) + off);
        bf16x8 ah0 = *(const bf16x8*)(sm + L_HS + (lr << 7) + off);
        bf16x8 ah1 = *(const bf16x8*)(sm + L_HS + ((16 + lr) << 7) + off);
        #pragma unroll
        for (int g = 0; g < 3; ++g) {
            int brow = (g << 6) + col;
            bf16x8 bi = *(const bf16x8*)(sm + L_WIS + (brow << 7) + off);
            bf16x8 bh = *(const bf16x8*)(sm + L_WHS + (brow << 7) + off);
            gi[0][g] = __builtin_amdgcn_mfma_f32_16x16x32_bf16(ay0, bi, gi[0][g], 0, 0, 0);
            gi[1][g] = __builtin_amdgcn_mfma_f32_16x16x32_bf16(ay1, bi, gi[1][g], 0, 0, 0);
            gh[0][g] = __builtin_amdgcn_mfma_f32_16x16x32_bf16(ah0, bh, gh[0][g], 0, 0, 0);
            gh[1][g] = __builtin_amdgcn_mfma_f32_16x16x32_bf16(ah1, bh, gh[1][g], 0, 0, 0);
        }
    }

    // --- epilogue: GRU gates (f32) + scatter store ---
    const int* idxp = (const int*)(sm + L_IDX);
    #pragma unroll
    for (int m = 0; m < 2; ++m) {
        #pragma unroll
        for (int r = 0; r < 4; ++r) {
            int node = (m << 4) + (lk << 2) + r;
            if (node < mcnt) {
                float rv = gi[m][0][r] + bir + gh[m][0][r] + bhr;
                float rg = 1.f / (1.f + __expf(-rv));
                float zv = gi[m][1][r] + biz + gh[m][1][r] + bhz;
                float zg = 1.f / (1.f + __expf(-zv));
                float ng = tanhf(gi[m][2][r] + bnn + rg * (gh[m][2][r] + bhn));
                float hold = *(const float*)(sm + L_HF + (node << 8) + (col << 2));
                out[(size_t)idxp[node] * OUTF + col] = (1.f - zg) * ng + zg * hold;
            }
        }
    }
}

extern "C" void kernel_launch(void* const* d_in, const int* in_sizes, int n_in,
                              void* d_out, int out_size, void* d_ws, size_t ws_size,
                              hipStream_t stream) {
    const float* agg   = (const float*)d_in[0];
    const float* h     = (const float*)d_in[1];
    const int*   ntype = (const int*)d_in[2];
    const float* W_att = (const float*)d_in[3];
    const float* b_att = (const float*)d_in[4];
    const float* W_in  = (const float*)d_in[5];
    const float* W_hid = (const float*)d_in[6];
    const float* b_in  = (const float*)d_in[7];
    const float* b_hid = (const float*)d_in[8];
    float* out = (float*)d_out;

    char* ws = (char*)d_ws;
    int* cursors = (int*)(ws + WS_CURS);
    int* perm = (int*)(ws + WS_PERM);
    unsigned short* waT = (unsigned short*)(ws + WS_WAT);
    unsigned short* wiT = (unsigned short*)(ws + WS_WIT);
    unsigned short* whT = (unsigned short*)(ws + WS_WHT);

    prep_weights<<<80, 256, 0, stream>>>(W_att, W_in, W_hid, cursors, waT, wiT, whT);
    scatter_by_type<<<N_NODES / 256, 256, 0, stream>>>(ntype, cursors, perm);
    fused_rgnn<<<MAXBLK, 256, 0, stream>>>(agg, h, cursors, perm,
        waT, wiT, whT, b_att, b_in, b_hid, out);
}

// Round 6
// 24.574 us; speedup vs baseline: 2.7315x; 1.4906x over previous
//
#include <hip/hip_runtime.h>

#define N_NODES 8192
#define T_TYPES 8
#define HIN 256     // H*IN
#define OUTF 64
#define G3 192      // 3*OUT
#define BM 32       // nodes per block
#define MAXBLK 264  // max total chunks = 8192/32 + 7 partials = 263
#define SCAT_BLKS 32

typedef __attribute__((ext_vector_type(8))) __bf16 bf16x8;
typedef __attribute__((ext_vector_type(4))) float f32x4;

// workspace byte offsets
#define WS_CURS 0
#define WS_PERM 256
#define WS_WAT  (256 + 262144)           // 8 types * 32768 B (bf16 [64][256], pre-swizzled)
#define WS_WIT  (WS_WAT + 262144)        // 8 types * 24576 B (bf16 [192][64], pre-swizzled)
#define WS_WHT  (WS_WIT + 196608)        // 8 types * 24576 B
#define WS_CNT  (WS_WHT + 196608)        // 32 blocks * 8 ints = 1024 B

// LDS byte offsets (fused kernel)
#define L_XS  0        // [32][256] bf16, swizzled           16384
#define L_WAS 16384    // WaT[64][256] bf16, swizzled        32768
#define L_WIS 49152    // WiT[192][64] bf16, swizzled        24576
#define L_WHS 73728    // WhT[192][64] bf16, swizzled        24576
#define L_YS  98304    // [32][64] bf16, swizzled             4096
#define L_HS  102400   // [32][64] bf16, swizzled             4096
#define L_HF  106496   // [32][64] f32, plain                 8192
#define L_IDX 114688   // 32 ints                              128
#define L_TOT 114816

#define GLD_LDS16(g, l) __builtin_amdgcn_global_load_lds( \
    (const __attribute__((address_space(1))) void*)(g),   \
    (__attribute__((address_space(3))) void*)(l), 16, 0, 0)

__device__ __forceinline__ unsigned short f2bf(float f) {
    unsigned u = __float_as_uint(f);
    return (unsigned short)((u + 0x7FFFu + ((u >> 16) & 1u)) >> 16);
}
__device__ __forceinline__ int pack2bf(float a, float b) {
    return (int)f2bf(a) | ((int)f2bf(b) << 16);
}

// K1: blocks 0-79 = weight transpose/bf16/pre-swizzle (as R5);
//     blocks 80-111 = per-block type histograms (pure writes, no global atomics).
__global__ __launch_bounds__(256) void prep_and_count(
    const float* __restrict__ W_att, const float* __restrict__ W_in,
    const float* __restrict__ W_hid, const int* __restrict__ nt,
    int* __restrict__ counts,
    unsigned short* __restrict__ waT, unsigned short* __restrict__ wiT,
    unsigned short* __restrict__ whT)
{
    __shared__ float Lf[64][68];   // prep path
    __shared__ int hist[8];        // count path
    const int tid = threadIdx.x;
    const int b = blockIdx.x;

    if (b >= 80) {                 // --- histogram blocks ---
        int j = b - 80;
        if (tid < 8) hist[tid] = 0;
        __syncthreads();
        int t = nt[j * 256 + tid];
        atomicAdd(&hist[t], 1);    // LDS atomic
        __syncthreads();
        if (tid < 8) counts[j * 8 + tid] = hist[tid];
        return;
    }

    const float* src;
    unsigned short* dstBase;
    int srcStride, rowBytes, colBase, rBase;

    if (b < 32) {
        int t = b >> 2, kt = b & 3;
        src = W_att + (((size_t)t * 256 + kt * 64) << 6);
        srcStride = 64;
        dstBase = waT + (size_t)t * 16384;
        rowBytes = 512; colBase = kt * 128; rBase = 0;
    } else {
        int j = b - 32;
        int isWh = (j >= 24); if (isWh) j -= 24;
        int t = j / 3, nt2 = j - t * 3;
        src = (isWh ? W_hid : W_in) + (size_t)t * 64 * 192 + nt2 * 64;
        srcStride = 192;
        dstBase = (isWh ? whT : wiT) + (size_t)t * 12288;
        rowBytes = 128; colBase = 0; rBase = nt2 * 64;
    }

    #pragma unroll
    for (int e = 0; e < 4; ++e) {
        int f = e * 256 + tid;            // float4 index within the 64x64 tile
        int kk = f >> 4, c = (f & 15) << 2;
        float4 v = *(const float4*)(src + kk * srcStride + c);
        Lf[kk][c] = v.x; Lf[kk][c + 1] = v.y; Lf[kk][c + 2] = v.z; Lf[kk][c + 3] = v.w;
    }
    __syncthreads();

    #pragma unroll
    for (int e = 0; e < 2; ++e) {
        int q = e * 256 + tid;
        int ko8 = q >> 6, rl = q & 63;
        int r = rBase + rl;
        unsigned short tmp[8];
        #pragma unroll
        for (int j2 = 0; j2 < 8; ++j2)
            tmp[j2] = f2bf(Lf[ko8 * 8 + j2][rl]);
        int4 wv;
        wv.x = (int)tmp[0] | ((int)tmp[1] << 16);
        wv.y = (int)tmp[2] | ((int)tmp[3] << 16);
        wv.z = (int)tmp[4] | ((int)tmp[5] << 16);
        wv.w = (int)tmp[6] | ((int)tmp[7] << 16);
        int B = r * rowBytes + colBase + ((ko8 << 4) ^ ((r & 7) << 4));
        *(int4*)((char*)dstBase + B) = wv;
    }
}

// K2: atomic-free scatter. Block j re-derives its per-type base from the count
// table (1 KB), scatters its 256 nodes via LDS cursors. Block 0 writes totals.
__global__ __launch_bounds__(256) void scatter_pass(
    const int* __restrict__ nt, const int* __restrict__ counts,
    int* __restrict__ cursors, int* __restrict__ perm)
{
    __shared__ int tbl[SCAT_BLKS * 8];
    __shared__ int cur[8];
    const int tid = threadIdx.x;
    const int j = blockIdx.x;

    tbl[tid & 255] = counts[tid & 255];   // 256 == SCAT_BLKS*8
    __syncthreads();
    if (tid < 8) {
        int base = 0, tot = 0;
        #pragma unroll
        for (int b = 0; b < SCAT_BLKS; ++b) {
            int c = tbl[b * 8 + tid];
            if (b < j) base += c;
            tot += c;
        }
        cur[tid] = base;
        if (j == 0) cursors[tid] = tot;
    }
    __syncthreads();
    int i = j * 256 + tid;
    int t = nt[i];
    int pos = atomicAdd(&cur[t], 1);      // LDS atomic
    perm[t * N_NODES + pos] = i;
}

__global__ __launch_bounds__(256) void fused_rgnn(
    const float* __restrict__ agg, const float* __restrict__ h,
    const int* __restrict__ cursors, const int* __restrict__ perm,
    const unsigned short* __restrict__ waT, const unsigned short* __restrict__ wiT,
    const unsigned short* __restrict__ whT,
    const float* __restrict__ b_att, const float* __restrict__ b_in,
    const float* __restrict__ b_hid, float* __restrict__ out)
{
    __shared__ __align__(16) char smem[L_TOT];
    char* sm = smem;

    const int tid = threadIdx.x;
    const int b = blockIdx.x;

    // Derive (type, chunk) from the 8 counts: prefix scan over ceil(cnt/BM).
    const int4 c0 = *(const int4*)cursors;
    const int4 c1 = *(const int4*)(cursors + 4);
    const int cntArr[8] = {c0.x, c0.y, c0.z, c0.w, c1.x, c1.y, c1.z, c1.w};
    int t = -1, chunk = 0, cnt = 0, acc = 0;
    #pragma unroll
    for (int tt = 0; tt < T_TYPES; ++tt) {
        int nc = (cntArr[tt] + BM - 1) >> 5;
        if (t < 0 && b < acc + nc) { t = tt; chunk = b - acc; cnt = cntArr[tt]; }
        acc += nc;
    }
    if (t < 0) return;                     // at most 8 blocks exit
    const int m0 = chunk * BM;
    const int mcnt = min(BM, cnt - m0);

    const int lane = tid & 63;
    const int w = tid >> 6;               // wave id: owns output cols 16w..16w+15
    const int lr = lane & 15;
    const int lk = lane >> 4;
    const int col = (w << 4) + lr;
    const int swzA = (lr & 7) << 4;

    // Biases (independent loads, issued early).
    const float ba  = b_att[(t << 6) + col];
    const float bir = b_in [t * G3 + col];
    const float biz = b_in [t * G3 + 64 + col];
    const float bnn = b_in [t * G3 + 128 + col];
    const float bhr = b_hid[t * G3 + col];
    const float bhz = b_hid[t * G3 + 64 + col];
    const float bhn = b_hid[t * G3 + 128 + col];

    // --- per-thread perm gathers (no barrier needed) ---
    const int nb = tid >> 5;              // X: node base, covers 4 nodes nb+8s
    const int kx = (tid & 31) << 3;       // 8 floats of the 256-wide row
    int xg[4];
    #pragma unroll
    for (int s = 0; s < 4; ++s) {
        int node = nb + (s << 3);
        xg[s] = (node < mcnt) ? perm[t * N_NODES + m0 + node] : -1;
    }
    const int nh = tid >> 3;              // H: node, 8 threads per node
    const int kh = (tid & 7) << 3;
    int hg = (nh < mcnt) ? perm[t * N_NODES + m0 + nh] : -1;

    // --- issue X/H f32 loads ---
    float4 xv[4][2];
    #pragma unroll
    for (int s = 0; s < 4; ++s) {
        if (xg[s] >= 0) {
            const float* p = agg + (size_t)xg[s] * HIN + kx;
            xv[s][0] = *(const float4*)p;
            xv[s][1] = *(const float4*)(p + 4);
        } else {
            xv[s][0] = make_float4(0.f, 0.f, 0.f, 0.f);
            xv[s][1] = make_float4(0.f, 0.f, 0.f, 0.f);
        }
    }
    float4 hv0, hv1;
    if (hg >= 0) {
        const float* p = h + (size_t)hg * OUTF + kh;
        hv0 = *(const float4*)p;
        hv1 = *(const float4*)(p + 4);
    } else {
        hv0 = make_float4(0.f, 0.f, 0.f, 0.f);
        hv1 = make_float4(0.f, 0.f, 0.f, 0.f);
    }

    // --- issue weight global->LDS DMA (20 x 16B/lane, stays in flight) ---
    {
        const char* was = (const char*)(waT + (size_t)t * 16384);
        const char* wis = (const char*)(wiT + (size_t)t * 12288);
        const char* whs = (const char*)(whT + (size_t)t * 12288);
        #pragma unroll
        for (int r = 0; r < 8; ++r) {     // 32KB = 32 x 1KB chunks
            int c = (r << 2) + w;
            GLD_LDS16(was + (c << 10) + (lane << 4), sm + L_WAS + (c << 10));
        }
        #pragma unroll
        for (int r = 0; r < 6; ++r) {     // 24KB = 24 x 1KB chunks
            int c = (r << 2) + w;
            GLD_LDS16(wis + (c << 10) + (lane << 4), sm + L_WIS + (c << 10));
            GLD_LDS16(whs + (c << 10) + (lane << 4), sm + L_WHS + (c << 10));
        }
    }

    // --- consume X: relu -> bf16 -> swizzled LDS ---
    #pragma unroll
    for (int s = 0; s < 4; ++s) {
        int node = nb + (s << 3);
        float4 a = xv[s][0], bq = xv[s][1];
        int4 wv;
        wv.x = pack2bf(fmaxf(a.x, 0.f), fmaxf(a.y, 0.f));
        wv.y = pack2bf(fmaxf(a.z, 0.f), fmaxf(a.w, 0.f));
        wv.z = pack2bf(fmaxf(bq.x, 0.f), fmaxf(bq.y, 0.f));
        wv.w = pack2bf(fmaxf(bq.z, 0.f), fmaxf(bq.w, 0.f));
        *(int4*)(sm + L_XS + (node << 9) + (((kx << 1)) ^ ((node & 7) << 4))) = wv;
    }
    // --- consume H: f32 copy + bf16 swizzled ---
    {
        *(float4*)(sm + L_HF + (nh << 8) + (kh << 2)) = hv0;
        *(float4*)(sm + L_HF + (nh << 8) + (kh << 2) + 16) = hv1;
        int4 wv;
        wv.x = pack2bf(hv0.x, hv0.y);
        wv.y = pack2bf(hv0.z, hv0.w);
        wv.z = pack2bf(hv1.x, hv1.y);
        wv.w = pack2bf(hv1.z, hv1.w);
        *(int4*)(sm + L_HS + (nh << 7) + ((kh << 1) ^ ((nh & 7) << 4))) = wv;
        if ((tid & 7) == 0) ((int*)(sm + L_IDX))[nh] = hg;
    }
    __syncthreads();   // drains weight DMA + LDS writes

    // --- phase 2: Y = relu(X @ Wa + ba), two 16x16 tiles per wave ---
    f32x4 acc0 = {0.f, 0.f, 0.f, 0.f}, acc1 = {0.f, 0.f, 0.f, 0.f};
    #pragma unroll
    for (int ks = 0; ks < 8; ++ks) {
        int koffB = (ks << 6) + (lk << 4);
        int off = koffB ^ swzA;
        bf16x8 bb = *(const bf16x8*)(sm + L_WAS + (((w << 4) + lr) << 9) + off);
        bf16x8 a0 = *(const bf16x8*)(sm + L_XS + (lr << 9) + off);
        bf16x8 a1 = *(const bf16x8*)(sm + L_XS + ((16 + lr) << 9) + off);
        acc0 = __builtin_amdgcn_mfma_f32_16x16x32_bf16(a0, bb, acc0, 0, 0, 0);
        acc1 = __builtin_amdgcn_mfma_f32_16x16x32_bf16(a1, bb, acc1, 0, 0, 0);
    }
    #pragma unroll
    for (int m = 0; m < 2; ++m) {
        #pragma unroll
        for (int r = 0; r < 4; ++r) {
            int row = (m << 4) + (lk << 2) + r;
            float y = fmaxf((m ? acc1[r] : acc0[r]) + ba, 0.f);
            *(unsigned short*)(sm + L_YS + (row << 7) +
                               (((col << 1)) ^ ((row & 7) << 4))) = f2bf(y);
        }
    }
    __syncthreads();

    // --- phase 3: gi = Y @ Wi, gh = H @ Wh; wave w owns gate cols 16w (r,z,n) ---
    f32x4 gi[2][3], gh[2][3];
    #pragma unroll
    for (int m = 0; m < 2; ++m)
        #pragma unroll
        for (int g = 0; g < 3; ++g) {
            gi[m][g] = (f32x4){0.f, 0.f, 0.f, 0.f};
            gh[m][g] = (f32x4){0.f, 0.f, 0.f, 0.f};
        }
    #pragma unroll
    for (int ks = 0; ks < 2; ++ks) {
        int off = ((ks << 6) + (lk << 4)) ^ swzA;
        bf16x8 ay0 = *(const bf16x8*)(sm + L_YS + (lr << 7) + off);
        bf16x8 ay1 = *(const bf16x8*)(sm + L_YS + ((16 + lr) << 7) + off);
        bf16x8 ah0 = *(const bf16x8*)(sm + L_HS + (lr << 7) + off);
        bf16x8 ah1 = *(const bf16x8*)(sm + L_HS + ((16 + lr) << 7) + off);
        #pragma unroll
        for (int g = 0; g < 3; ++g) {
            int brow = (g << 6) + col;
            bf16x8 bi = *(const bf16x8*)(sm + L_WIS + (brow << 7) + off);
            bf16x8 bh = *(const bf16x8*)(sm + L_WHS + (brow << 7) + off);
            gi[0][g] = __builtin_amdgcn_mfma_f32_16x16x32_bf16(ay0, bi, gi[0][g], 0, 0, 0);
            gi[1][g] = __builtin_amdgcn_mfma_f32_16x16x32_bf16(ay1, bi, gi[1][g], 0, 0, 0);
            gh[0][g] = __builtin_amdgcn_mfma_f32_16x16x32_bf16(ah0, bh, gh[0][g], 0, 0, 0);
            gh[1][g] = __builtin_amdgcn_mfma_f32_16x16x32_bf16(ah1, bh, gh[1][g], 0, 0, 0);
        }
    }

    // --- epilogue: GRU gates (f32) + scatter store ---
    const int* idxp = (const int*)(sm + L_IDX);
    #pragma unroll
    for (int m = 0; m < 2; ++m) {
        #pragma unroll
        for (int r = 0; r < 4; ++r) {
            int node = (m << 4) + (lk << 2) + r;
            if (node < mcnt) {
                float rv = gi[m][0][r] + bir + gh[m][0][r] + bhr;
                float rg = 1.f / (1.f + __expf(-rv));
                float zv = gi[m][1][r] + biz + gh[m][1][r] + bhz;
                float zg = 1.f / (1.f + __expf(-zv));
                float ng = tanhf(gi[m][2][r] + bnn + rg * (gh[m][2][r] + bhn));
                float hold = *(const float*)(sm + L_HF + (node << 8) + (col << 2));
                out[(size_t)idxp[node] * OUTF + col] = (1.f - zg) * ng + zg * hold;
            }
        }
    }
}

extern "C" void kernel_launch(void* const* d_in, const int* in_sizes, int n_in,
                              void* d_out, int out_size, void* d_ws, size_t ws_size,
                              hipStream_t stream) {
    const float* agg   = (const float*)d_in[0];
    const float* h     = (const float*)d_in[1];
    const int*   ntype = (const int*)d_in[2];
    const float* W_att = (const float*)d_in[3];
    const float* b_att = (const float*)d_in[4];
    const float* W_in  = (const float*)d_in[5];
    const float* W_hid = (const float*)d_in[6];
    const float* b_in  = (const float*)d_in[7];
    const float* b_hid = (const float*)d_in[8];
    float* out = (float*)d_out;

    char* ws = (char*)d_ws;
    int* cursors = (int*)(ws + WS_CURS);
    int* perm = (int*)(ws + WS_PERM);
    unsigned short* waT = (unsigned short*)(ws + WS_WAT);
    unsigned short* wiT = (unsigned short*)(ws + WS_WIT);
    unsigned short* whT = (unsigned short*)(ws + WS_WHT);
    int* counts = (int*)(ws + WS_CNT);

    prep_and_count<<<112, 256, 0, stream>>>(W_att, W_in, W_hid, ntype, counts, waT, wiT, whT);
    scatter_pass<<<SCAT_BLKS, 256, 0, stream>>>(ntype, counts, cursors, perm);
    fused_rgnn<<<MAXBLK, 256, 0, stream>>>(agg, h, cursors, perm,
        waT, wiT, whT, b_att, b_in, b_hid, out);
}